// Round 19
// baseline (122.527 us; speedup 1.0000x reference)
//
#include <hip/hip_runtime.h>

typedef __attribute__((ext_vector_type(8))) __bf16 bf16x8;
typedef __attribute__((ext_vector_type(4))) float f32x4;

constexpr float NEG = 1000000000000.0f;  // NEG_INF

static __device__ __forceinline__ unsigned short f2bf(float f) {
    unsigned int u = __float_as_uint(f);
    u += 0x7FFFu + ((u >> 16) & 1u);   // round-to-nearest-even
    return (unsigned short)(u >> 16);
}

static __device__ __forceinline__ void gload16(const unsigned short* g, unsigned short* l) {
    __builtin_amdgcn_global_load_lds((const __attribute__((address_space(1))) void*)g,
                                     (__attribute__((address_space(3))) void*)l, 16, 0, 0);
}

// ---------------- fused prep: convX | transW | sincos ----------------
__global__ __launch_bounds__(256) void k_prep(const float* __restrict__ X,
                                              unsigned short* __restrict__ Xb,
                                              const float* __restrict__ W,
                                              unsigned short* __restrict__ WT,
                                              float* __restrict__ ct,
                                              float* __restrict__ st) {
    __shared__ __align__(16) unsigned short T[64][72];
    const int bid = blockIdx.x;
    const int tid = threadIdx.x;
    if (bid < 2048) {
        int idx = bid * 256 + tid;
        for (; idx < 1572864; idx += 2048 * 256) {
            float4 v = reinterpret_cast<const float4*>(X)[idx];
            ushort4 o;
            o.x = f2bf(v.x); o.y = f2bf(v.y); o.z = f2bf(v.z); o.w = f2bf(v.w);
            reinterpret_cast<ushort4*>(Xb)[idx] = o;
        }
    } else if (bid < 2264) {
        const int t = bid - 2048;
        const int k0 = (t % 12) * 64;
        const int c0 = (t / 12) * 64;
        const int r = tid >> 2;
        const int q = tid & 3;
        const float* src = W + (k0 + r) * 1152 + c0 + q * 16;
#pragma unroll
        for (int j = 0; j < 16; ++j)
            T[q * 16 + j][r] = f2bf(src[j]);
        __syncthreads();
        unsigned short* dst = WT + (c0 + r) * 768 + k0 + q * 16;
        *reinterpret_cast<uint4*>(dst)     = *reinterpret_cast<const uint4*>(&T[r][q * 16]);
        *reinterpret_cast<uint4*>(dst + 8) = *reinterpret_cast<const uint4*>(&T[r][q * 16 + 8]);
    } else {
        int idx = (bid - 2264) * 256 + tid;   // 0..32767
        int pos = idx >> 5, i = idx & 31;
        double inv = exp(-9.210340371976184 * (double)(2 * i) / 64.0);  // 10000^(-2i/64)
        double ang = (double)pos * inv;
        ct[idx] = (float)cos(ang);
        st[idx] = (float)sin(ang);
    }
}

// ---------------- projection+RoPE (XCD-congruent) + fill ----------------
// proj bids [0,576): bid = 8*((panel/8)*9 + h) + panel%8 (r13 locality).
// Epilogue now LDS-staged: Q/K tiles (128x64) written to padded LDS, then
// copied out as 4KB-contiguous wave runs (r18's proven store-contiguity fix).
// fill bids [576,2592): contiguous 512B row-segment stores (r18).
__global__ __launch_bounds__(256) void k_projfill(const unsigned short* __restrict__ Xb,
                                                  const unsigned short* __restrict__ WT,
                                                  const float* __restrict__ bias,
                                                  const float* __restrict__ ct,
                                                  const float* __restrict__ st,
                                                  unsigned short* __restrict__ Qb,
                                                  unsigned short* __restrict__ Kb,
                                                  const float* __restrict__ pmask,
                                                  float* __restrict__ out) {
    __shared__ __align__(16) unsigned short SM[2 * 128 * 72];   // 36864 B
    unsigned short* As = SM;                 // [128*32] during K-loop
    unsigned short* Bs = SM + 4096;          // [128*32]
    unsigned short* Qlds = SM;               // [128][72] after K-loop
    unsigned short* Klds = SM + 9216;        // [128][72]
    const int bid = blockIdx.x;
    const int tid = threadIdx.x;

    if (bid >= 576) {
        // ---- fill block: one fully-masked 128x128 tile, contiguous stores --
        const int fid = bid - 576;
        const int bh = fid / 28;
        int j = fid % 28;
        int tm = 1, tn = 0;
#pragma unroll
        for (int t = 1; t < 8; ++t) {
            if (j < t) { tm = t; tn = j; break; }
            j -= t;
        }
        const int m0 = tm << 7, n0 = tn << 7;
        float* outb = out + (long long)bh * 1048576;
        const float* pm = pmask + (bh / 9) * 1024;
        const int cr = tid >> 5;             // row sub-index 0..7
        const int cc = (tid & 31) * 4;       // col 0..124
        f32x4 p = *reinterpret_cast<const f32x4*>(pm + n0 + cc);
        f32x4 o;
        o[0] = (-(1.0f - p[0]) * NEG - NEG) * 0.125f;
        o[1] = (-(1.0f - p[1]) * NEG - NEG) * 0.125f;
        o[2] = (-(1.0f - p[2]) * NEG - NEG) * 0.125f;
        o[3] = (-(1.0f - p[3]) * NEG - NEG) * 0.125f;
#pragma unroll
        for (int v = 0; v < 16; ++v) {
            const int r = v * 8 + cr;
            *reinterpret_cast<f32x4*>(outb + (long long)(m0 + r) * 1024 + n0 + cc) = o;
        }
        return;
    }

    // ---- proj block: decode XCD-congruent mapping ----
    const int x = bid & 7;               // XCD
    const int jj = bid >> 3;             // 0..71
    const int panel = (jj / 9) * 8 + x;  // 0..63
    const int h = jj % 9;
    const int lane = tid & 63;
    const int w = tid >> 6;
    const int wr = w >> 1, wc = w & 1;
    const int m0 = panel * 128;
    const int c0 = h * 128;

    const int l15 = lane & 15;
    const int lchunk = lane >> 4;

    const int srow0 = w * 16 + (lane >> 2);
    const int cphys = lane & 3;
    const int kl0 = cphys ^ ((srow0 >> 1) & 3);
    const int kl1 = cphys ^ (((srow0 + 64) >> 1) & 3);
    unsigned short* ldsA0 = As + w * 512 + lane * 8;
    unsigned short* ldsA1 = As + 2048 + w * 512 + lane * 8;
    unsigned short* ldsB0 = Bs + w * 512 + lane * 8;
    unsigned short* ldsB1 = Bs + 2048 + w * 512 + lane * 8;
    const unsigned short* gA0 = Xb + (m0 + srow0) * 768 + kl0 * 8;
    const unsigned short* gA1 = Xb + (m0 + srow0 + 64) * 768 + kl1 * 8;
    const unsigned short* gB0 = WT + (c0 + srow0) * 768 + kl0 * 8;
    const unsigned short* gB1 = WT + (c0 + srow0 + 64) * 768 + kl1 * 8;

    f32x4 acc[4][4] = {};

    for (int kt = 0; kt < 24; ++kt) {
        const int k0 = kt * 32;
        __syncthreads();
        gload16(gA0 + k0, ldsA0);
        gload16(gA1 + k0, ldsA1);
        gload16(gB0 + k0, ldsB0);
        gload16(gB1 + k0, ldsB1);
        __syncthreads();

        bf16x8 a[4], bfr[4];
#pragma unroll
        for (int mi = 0; mi < 4; ++mi) {
            const int row = wr * 64 + mi * 16 + l15;
            const int pc = lchunk ^ ((row >> 1) & 3);
            a[mi] = *reinterpret_cast<const bf16x8*>(As + row * 32 + pc * 8);
        }
#pragma unroll
        for (int ni = 0; ni < 4; ++ni) {
            const int row = wc * 64 + ni * 16 + l15;
            const int pc = lchunk ^ ((row >> 1) & 3);
            bfr[ni] = *reinterpret_cast<const bf16x8*>(Bs + row * 32 + pc * 8);
        }
        // swapped operands: D-row <- W cols (c128), D-col <- X rows (s)
#pragma unroll
        for (int mi = 0; mi < 4; ++mi)
#pragma unroll
            for (int ni = 0; ni < 4; ++ni)
                acc[mi][ni] = __builtin_amdgcn_mfma_f32_16x16x32_bf16(bfr[ni], a[mi], acc[mi][ni], 0, 0, 0);
    }

    __syncthreads();   // As/Bs reads done; SM becomes Qlds/Klds

    // epilogue: bias + RoPE -> bf16 -> LDS tiles (72-short padded rows)
    const int qrow = (lane >> 4) << 2;
#pragma unroll
    for (int mi = 0; mi < 4; ++mi) {
        const int rl = wr * 64 + mi * 16 + l15;          // tile row 0..127
        const int s = (m0 + rl) & 1023;
        const float* cts = ct + s * 32;
        const float* sts = st + s * 32;
#pragma unroll
        for (int ni = 0; ni < 4; ++ni) {
            const int base = wc * 64 + ni * 16 + qrow;   // c128 of reg 0
            const int isK = base >> 6;
            const int d0 = base & 63;
            const int fi = d0 >> 1;
            f32x4 v = acc[mi][ni];
            f32x4 bq = *reinterpret_cast<const f32x4*>(bias + c0 + base);
            v[0] += bq[0]; v[1] += bq[1]; v[2] += bq[2]; v[3] += bq[3];
            const float cv0 = cts[fi],     sv0 = sts[fi];
            const float cv1 = cts[fi + 1], sv1 = sts[fi + 1];
            ushort4 o;
            o.x = f2bf(v[0] * cv0 - v[1] * sv0);
            o.y = f2bf(v[1] * cv0 + v[0] * sv0);
            o.z = f2bf(v[2] * cv1 - v[3] * sv1);
            o.w = f2bf(v[3] * cv1 + v[2] * sv1);
            unsigned short* t = (isK ? Klds : Qlds) + rl * 72 + d0;
            *reinterpret_cast<ushort4*>(t) = o;
        }
    }
    __syncthreads();

    // contiguous copy-out: Q and K strips are each 16 KB contiguous in global
    {
        const int bb = m0 >> 10;
        const int s0 = m0 & 1023;
        const long long gb = ((long long)((bb * 9 + h) * 1024 + s0)) << 6;
        const int r = tid >> 1;              // 0..127
        const int cbase = (tid & 1) * 32;    // shorts
#pragma unroll
        for (int i = 0; i < 4; ++i) {
            const int c = cbase + i * 8;
            *reinterpret_cast<uint4*>(Qb + gb + r * 64 + c) =
                *reinterpret_cast<const uint4*>(Qlds + r * 72 + c);
        }
#pragma unroll
        for (int i = 0; i < 4; ++i) {
            const int c = cbase + i * 8;
            *reinterpret_cast<uint4*>(Kb + gb + r * 64 + c) =
                *reinterpret_cast<const uint4*>(Klds + r * 72 + c);
        }
    }
}

// ---------------- scores: paired tiles, LDS-staged CONTIGUOUS C-writes --
__constant__ int PT_TM[20]  = {0,0,0,0, 1,1,1,1, 2,2,2, 3,3,3, 4,4, 5,5, 6, 7};
__constant__ int PT_TN[20]  = {0,2,4,6, 1,3,5,7, 2,4,6, 3,5,7, 4,6, 5,7, 6, 7};
__constant__ int PT_CNT[20] = {2,2,2,2, 2,2,2,1, 2,2,2, 2,2,1, 2,2, 2,1, 2, 1};

__global__ __launch_bounds__(256) void k_score(const unsigned short* __restrict__ Qb,
                                               const unsigned short* __restrict__ Kb,
                                               const float* __restrict__ pmask,
                                               float* __restrict__ out) {
    __shared__ __align__(16) float Cs[64 * 132];   // 33792 B, 16B-aligned rows
    const int bh = blockIdx.y;
    const int pi = blockIdx.x;          // 0..19
    const int tm = PT_TM[pi];
    const int tn0 = PT_TN[pi];
    const int cnt = PT_CNT[pi];
    const int m0 = tm << 7;
    const int tid = threadIdx.x;
    float* outb = out + (long long)bh * 1048576;
    const float* pm = pmask + (bh / 9) * 1024;

    const int lane = tid & 63;
    const int w = tid >> 6;
    const int wr = w >> 1, wc = w & 1;
    const int l15 = lane & 15;
    const int kfr = (lane >> 4) * 8;
    const unsigned short* qb = Qb + bh * 65536;
    const unsigned short* kb = Kb + bh * 65536;

    bf16x8 a[4][2];
#pragma unroll
    for (int mi = 0; mi < 4; ++mi)
#pragma unroll
        for (int kk = 0; kk < 2; ++kk)
            a[mi][kk] = *reinterpret_cast<const bf16x8*>(qb + (m0 + wr * 64 + mi * 16 + l15) * 64 + kk * 32 + kfr);

    const int colq = (lane >> 4) << 2;
    const int cr = tid >> 5;             // copy-out row sub-index 0..7
    const int cc = (tid & 31) * 4;       // copy-out col 0..124

    for (int nt = 0; nt < cnt; ++nt) {
        const int n0 = (tn0 + nt) << 7;
        bf16x8 b[4][2];
#pragma unroll
        for (int ni = 0; ni < 4; ++ni)
#pragma unroll
            for (int kk = 0; kk < 2; ++kk)
                b[ni][kk] = *reinterpret_cast<const bf16x8*>(kb + (n0 + wc * 64 + ni * 16 + l15) * 64 + kk * 32 + kfr);

        f32x4 acc[4][4] = {};
#pragma unroll
        for (int mi = 0; mi < 4; ++mi)
#pragma unroll
            for (int ni = 0; ni < 4; ++ni) {
                acc[mi][ni] = __builtin_amdgcn_mfma_f32_16x16x32_bf16(b[ni][0], a[mi][0], acc[mi][ni], 0, 0, 0);
                acc[mi][ni] = __builtin_amdgcn_mfma_f32_16x16x32_bf16(b[ni][1], a[mi][1], acc[mi][ni], 0, 0, 0);
            }

        f32x4 pmq[4];
#pragma unroll
        for (int ni = 0; ni < 4; ++ni)
            pmq[ni] = *reinterpret_cast<const f32x4*>(pm + n0 + wc * 64 + ni * 16 + colq);

#pragma unroll
        for (int half = 0; half < 2; ++half) {
            __syncthreads();   // previous copy-out (or tile) done
#pragma unroll
            for (int mi2 = 0; mi2 < 2; ++mi2) {
                const int mi = half * 2 + mi2;
                const int row = m0 + wr * 64 + mi * 16 + l15;
                const int lr = wr * 32 + mi2 * 16 + l15;      // 0..63
#pragma unroll
                for (int ni = 0; ni < 4; ++ni) {
                    const int colb = n0 + wc * 64 + ni * 16 + colq;
                    const f32x4 d = acc[mi][ni];
                    f32x4 o;
                    o[0] = (d[0] * pmq[ni][0] - (1.0f - pmq[ni][0]) * NEG - ((colb + 0 < row) ? NEG : 0.0f)) * 0.125f;
                    o[1] = (d[1] * pmq[ni][1] - (1.0f - pmq[ni][1]) * NEG - ((colb + 1 < row) ? NEG : 0.0f)) * 0.125f;
                    o[2] = (d[2] * pmq[ni][2] - (1.0f - pmq[ni][2]) * NEG - ((colb + 2 < row) ? NEG : 0.0f)) * 0.125f;
                    o[3] = (d[3] * pmq[ni][3] - (1.0f - pmq[ni][3]) * NEG - ((colb + 3 < row) ? NEG : 0.0f)) * 0.125f;
                    *reinterpret_cast<f32x4*>(&Cs[lr * 132 + wc * 64 + ni * 16 + colq]) = o;
                }
            }
            __syncthreads();
            // contiguous copy-out: 64 rows x 128 cols
#pragma unroll
            for (int v = 0; v < 8; ++v) {
                const int lr = v * 8 + cr;
                const int orow = m0 + (lr >> 5) * 64 + half * 32 + (lr & 31);
                f32x4 val = *reinterpret_cast<const f32x4*>(&Cs[lr * 132 + cc]);
                *reinterpret_cast<f32x4*>(outb + (long long)orow * 1024 + n0 + cc) = val;
            }
        }
    }
}

extern "C" void kernel_launch(void* const* d_in, const int* in_sizes, int n_in,
                              void* d_out, int out_size, void* d_ws, size_t ws_size,
                              hipStream_t stream) {
    const float* X    = (const float*)d_in[0];
    const float* pm   = (const float*)d_in[1];
    const float* W    = (const float*)d_in[2];
    const float* bias = (const float*)d_in[3];
    char* ws = (char*)d_ws;
    unsigned short* Xb = (unsigned short*)(ws + 0);          // 8192x768 bf16
    unsigned short* WT = (unsigned short*)(ws + 12582912);   // 1152x768 bf16
    unsigned short* Qb = (unsigned short*)(ws + 14352384);   // 72x1024x64 bf16
    unsigned short* Kb = (unsigned short*)(ws + 23789568);   // 72x1024x64 bf16
    float* ct = (float*)(ws + 33226752);                     // 1024x32 f32
    float* st = (float*)(ws + 33357824);                     // 1024x32 f32
    float* out = (float*)d_out;

    hipLaunchKernelGGL(k_prep, dim3(2392), dim3(256), 0, stream, X, Xb, W, WT, ct, st);
    hipLaunchKernelGGL(k_projfill, dim3(2592), dim3(256), 0, stream, Xb, WT, bias, ct, st, Qb, Kb, pm, out);
    hipLaunchKernelGGL(k_score, dim3(20, 72), dim3(256), 0, stream, Qb, Kb, pm, out);
}

// Round 20
// 104.008 us; speedup vs baseline: 1.1781x; 1.1781x over previous
//
#include <hip/hip_runtime.h>

typedef __attribute__((ext_vector_type(8))) __bf16 bf16x8;
typedef __attribute__((ext_vector_type(4))) float f32x4;

constexpr float NEG = 1000000000000.0f;  // NEG_INF

static __device__ __forceinline__ unsigned short f2bf(float f) {
    unsigned int u = __float_as_uint(f);
    u += 0x7FFFu + ((u >> 16) & 1u);   // round-to-nearest-even
    return (unsigned short)(u >> 16);
}

static __device__ __forceinline__ void gload16(const unsigned short* g, unsigned short* l) {
    __builtin_amdgcn_global_load_lds((const __attribute__((address_space(1))) void*)g,
                                     (__attribute__((address_space(3))) void*)l, 16, 0, 0);
}

// ---------------- fused prep: convX | transW | sincos ----------------
__global__ __launch_bounds__(256) void k_prep(const float* __restrict__ X,
                                              unsigned short* __restrict__ Xb,
                                              const float* __restrict__ W,
                                              unsigned short* __restrict__ WT,
                                              float* __restrict__ ct,
                                              float* __restrict__ st) {
    __shared__ __align__(16) unsigned short T[64][72];
    const int bid = blockIdx.x;
    const int tid = threadIdx.x;
    if (bid < 2048) {
        int idx = bid * 256 + tid;
        for (; idx < 1572864; idx += 2048 * 256) {
            float4 v = reinterpret_cast<const float4*>(X)[idx];
            ushort4 o;
            o.x = f2bf(v.x); o.y = f2bf(v.y); o.z = f2bf(v.z); o.w = f2bf(v.w);
            reinterpret_cast<ushort4*>(Xb)[idx] = o;
        }
    } else if (bid < 2264) {
        const int t = bid - 2048;
        const int k0 = (t % 12) * 64;
        const int c0 = (t / 12) * 64;
        const int r = tid >> 2;
        const int q = tid & 3;
        const float* src = W + (k0 + r) * 1152 + c0 + q * 16;
#pragma unroll
        for (int j = 0; j < 16; ++j)
            T[q * 16 + j][r] = f2bf(src[j]);
        __syncthreads();
        unsigned short* dst = WT + (c0 + r) * 768 + k0 + q * 16;
        *reinterpret_cast<uint4*>(dst)     = *reinterpret_cast<const uint4*>(&T[r][q * 16]);
        *reinterpret_cast<uint4*>(dst + 8) = *reinterpret_cast<const uint4*>(&T[r][q * 16 + 8]);
    } else {
        int idx = (bid - 2264) * 256 + tid;   // 0..32767
        int pos = idx >> 5, i = idx & 31;
        double inv = exp(-9.210340371976184 * (double)(2 * i) / 64.0);  // 10000^(-2i/64)
        double ang = (double)pos * inv;
        ct[idx] = (float)cos(ang);
        st[idx] = (float)sin(ang);
    }
}

// ---------------- projection (512-thread, 8-wave) + fill ----------------
// proj bids [0,576): 128x128 tile, 8 waves each computing 64x32 output.
// 512 threads double resident waves/CU (9 -> 18) to hide the per-K-step
// vmcnt+barrier drain. XCD-congruent: bid = 8*((panel/8)*9+h) + panel%8.
// fill bids [576,2592): contiguous 512B row-segment stores (r18).
__global__ __launch_bounds__(512) void k_projfill(const unsigned short* __restrict__ Xb,
                                                  const unsigned short* __restrict__ WT,
                                                  const float* __restrict__ bias,
                                                  const float* __restrict__ ct,
                                                  const float* __restrict__ st,
                                                  unsigned short* __restrict__ Qb,
                                                  unsigned short* __restrict__ Kb,
                                                  const float* __restrict__ pmask,
                                                  float* __restrict__ out) {
    __shared__ __align__(16) unsigned short As[128 * 32];
    __shared__ __align__(16) unsigned short Bs[128 * 32];
    const int bid = blockIdx.x;
    const int tid = threadIdx.x;

    if (bid >= 576) {
        // ---- fill block: one fully-masked 128x128 tile, contiguous stores --
        const int fid = bid - 576;
        const int bh = fid / 28;
        int j = fid % 28;
        int tm = 1, tn = 0;
#pragma unroll
        for (int t = 1; t < 8; ++t) {
            if (j < t) { tm = t; tn = j; break; }
            j -= t;
        }
        const int m0 = tm << 7, n0 = tn << 7;
        float* outb = out + (long long)bh * 1048576;
        const float* pm = pmask + (bh / 9) * 1024;
        const int cr = tid >> 5;             // row sub-index 0..15
        const int cc = (tid & 31) * 4;       // col 0..124
        f32x4 p = *reinterpret_cast<const f32x4*>(pm + n0 + cc);
        f32x4 o;
        o[0] = (-(1.0f - p[0]) * NEG - NEG) * 0.125f;
        o[1] = (-(1.0f - p[1]) * NEG - NEG) * 0.125f;
        o[2] = (-(1.0f - p[2]) * NEG - NEG) * 0.125f;
        o[3] = (-(1.0f - p[3]) * NEG - NEG) * 0.125f;
#pragma unroll
        for (int v = 0; v < 8; ++v) {
            const int r = v * 16 + cr;
            *reinterpret_cast<f32x4*>(outb + (long long)(m0 + r) * 1024 + n0 + cc) = o;
        }
        return;
    }

    // ---- proj block: decode XCD-congruent mapping ----
    const int x = bid & 7;               // XCD
    const int jj = bid >> 3;             // 0..71
    const int panel = (jj / 9) * 8 + x;  // 0..63
    const int h = jj % 9;
    const int lane = tid & 63;
    const int w = tid >> 6;              // 0..7
    const int wm = w >> 2;               // M-half 0..1
    const int wn = w & 3;                // N-quarter 0..3
    const int m0 = panel * 128;
    const int c0 = h * 128;

    const int l15 = lane & 15;
    const int lchunk = lane >> 4;

    // staging: one A-row-chunk + one B-row-chunk per thread
    const int srow = tid >> 2;           // 0..127
    const int kl = (tid & 3) ^ ((srow >> 1) & 3);
    unsigned short* ldsA = As + tid * 8;
    unsigned short* ldsB = Bs + tid * 8;
    const unsigned short* gA = Xb + (m0 + srow) * 768 + kl * 8;
    const unsigned short* gB = WT + (c0 + srow) * 768 + kl * 8;

    f32x4 acc[4][2] = {};

    for (int kt = 0; kt < 24; ++kt) {
        const int k0 = kt * 32;
        __syncthreads();
        gload16(gA + k0, ldsA);
        gload16(gB + k0, ldsB);
        __syncthreads();

        bf16x8 a[4], bfr[2];
#pragma unroll
        for (int mi = 0; mi < 4; ++mi) {
            const int row = wm * 64 + mi * 16 + l15;
            const int pc = lchunk ^ ((row >> 1) & 3);
            a[mi] = *reinterpret_cast<const bf16x8*>(As + row * 32 + pc * 8);
        }
#pragma unroll
        for (int ni = 0; ni < 2; ++ni) {
            const int row = wn * 32 + ni * 16 + l15;
            const int pc = lchunk ^ ((row >> 1) & 3);
            bfr[ni] = *reinterpret_cast<const bf16x8*>(Bs + row * 32 + pc * 8);
        }
        // swapped operands: D-row <- W cols (c128), D-col <- X rows (s)
#pragma unroll
        for (int mi = 0; mi < 4; ++mi)
#pragma unroll
            for (int ni = 0; ni < 2; ++ni)
                acc[mi][ni] = __builtin_amdgcn_mfma_f32_16x16x32_bf16(bfr[ni], a[mi], acc[mi][ni], 0, 0, 0);
    }

    // epilogue (r18 style: direct scattered ushort4 — measured best)
    const int qrow = (lane >> 4) << 2;
#pragma unroll
    for (int mi = 0; mi < 4; ++mi) {
        const int grow = m0 + wm * 64 + mi * 16 + l15;   // global X row
        const int bb = grow >> 10;
        const int s = grow & 1023;
        const float* cts = ct + s * 32;
        const float* sts = st + s * 32;
        const long long obase = (long long)(((bb * 9 + h) * 1024 + s)) << 6;
#pragma unroll
        for (int ni = 0; ni < 2; ++ni) {
            const int base = wn * 32 + ni * 16 + qrow;   // c128 of reg 0
            const int isK = base >> 6;
            const int d0 = base & 63;
            const int fi = d0 >> 1;
            f32x4 v = acc[mi][ni];
            f32x4 bq = *reinterpret_cast<const f32x4*>(bias + c0 + base);
            v[0] += bq[0]; v[1] += bq[1]; v[2] += bq[2]; v[3] += bq[3];
            const float cv0 = cts[fi],     sv0 = sts[fi];
            const float cv1 = cts[fi + 1], sv1 = sts[fi + 1];
            ushort4 o;
            o.x = f2bf(v[0] * cv0 - v[1] * sv0);
            o.y = f2bf(v[1] * cv0 + v[0] * sv0);
            o.z = f2bf(v[2] * cv1 - v[3] * sv1);
            o.w = f2bf(v[3] * cv1 + v[2] * sv1);
            unsigned short* dst0 = isK ? Kb : Qb;
            *reinterpret_cast<ushort4*>(dst0 + obase + d0) = o;
        }
    }
}

// ---------------- scores: paired tiles, LDS-staged CONTIGUOUS C-writes --
__constant__ int PT_TM[20]  = {0,0,0,0, 1,1,1,1, 2,2,2, 3,3,3, 4,4, 5,5, 6, 7};
__constant__ int PT_TN[20]  = {0,2,4,6, 1,3,5,7, 2,4,6, 3,5,7, 4,6, 5,7, 6, 7};
__constant__ int PT_CNT[20] = {2,2,2,2, 2,2,2,1, 2,2,2, 2,2,1, 2,2, 2,1, 2, 1};

__global__ __launch_bounds__(256) void k_score(const unsigned short* __restrict__ Qb,
                                               const unsigned short* __restrict__ Kb,
                                               const float* __restrict__ pmask,
                                               float* __restrict__ out) {
    __shared__ __align__(16) float Cs[64 * 132];   // 33792 B, 16B-aligned rows
    const int bh = blockIdx.y;
    const int pi = blockIdx.x;          // 0..19
    const int tm = PT_TM[pi];
    const int tn0 = PT_TN[pi];
    const int cnt = PT_CNT[pi];
    const int m0 = tm << 7;
    const int tid = threadIdx.x;
    float* outb = out + (long long)bh * 1048576;
    const float* pm = pmask + (bh / 9) * 1024;

    const int lane = tid & 63;
    const int w = tid >> 6;
    const int wr = w >> 1, wc = w & 1;
    const int l15 = lane & 15;
    const int kfr = (lane >> 4) * 8;
    const unsigned short* qb = Qb + bh * 65536;
    const unsigned short* kb = Kb + bh * 65536;

    bf16x8 a[4][2];
#pragma unroll
    for (int mi = 0; mi < 4; ++mi)
#pragma unroll
        for (int kk = 0; kk < 2; ++kk)
            a[mi][kk] = *reinterpret_cast<const bf16x8*>(qb + (m0 + wr * 64 + mi * 16 + l15) * 64 + kk * 32 + kfr);

    const int colq = (lane >> 4) << 2;
    const int cr = tid >> 5;             // copy-out row sub-index 0..7
    const int cc = (tid & 31) * 4;       // copy-out col 0..124

    for (int nt = 0; nt < cnt; ++nt) {
        const int n0 = (tn0 + nt) << 7;
        bf16x8 b[4][2];
#pragma unroll
        for (int ni = 0; ni < 4; ++ni)
#pragma unroll
            for (int kk = 0; kk < 2; ++kk)
                b[ni][kk] = *reinterpret_cast<const bf16x8*>(kb + (n0 + wc * 64 + ni * 16 + l15) * 64 + kk * 32 + kfr);

        f32x4 acc[4][4] = {};
#pragma unroll
        for (int mi = 0; mi < 4; ++mi)
#pragma unroll
            for (int ni = 0; ni < 4; ++ni) {
                acc[mi][ni] = __builtin_amdgcn_mfma_f32_16x16x32_bf16(b[ni][0], a[mi][0], acc[mi][ni], 0, 0, 0);
                acc[mi][ni] = __builtin_amdgcn_mfma_f32_16x16x32_bf16(b[ni][1], a[mi][1], acc[mi][ni], 0, 0, 0);
            }

        f32x4 pmq[4];
#pragma unroll
        for (int ni = 0; ni < 4; ++ni)
            pmq[ni] = *reinterpret_cast<const f32x4*>(pm + n0 + wc * 64 + ni * 16 + colq);

#pragma unroll
        for (int half = 0; half < 2; ++half) {
            __syncthreads();   // previous copy-out (or tile) done
#pragma unroll
            for (int mi2 = 0; mi2 < 2; ++mi2) {
                const int mi = half * 2 + mi2;
                const int row = m0 + wr * 64 + mi * 16 + l15;
                const int lr = wr * 32 + mi2 * 16 + l15;      // 0..63
#pragma unroll
                for (int ni = 0; ni < 4; ++ni) {
                    const int colb = n0 + wc * 64 + ni * 16 + colq;
                    const f32x4 d = acc[mi][ni];
                    f32x4 o;
                    o[0] = (d[0] * pmq[ni][0] - (1.0f - pmq[ni][0]) * NEG - ((colb + 0 < row) ? NEG : 0.0f)) * 0.125f;
                    o[1] = (d[1] * pmq[ni][1] - (1.0f - pmq[ni][1]) * NEG - ((colb + 1 < row) ? NEG : 0.0f)) * 0.125f;
                    o[2] = (d[2] * pmq[ni][2] - (1.0f - pmq[ni][2]) * NEG - ((colb + 2 < row) ? NEG : 0.0f)) * 0.125f;
                    o[3] = (d[3] * pmq[ni][3] - (1.0f - pmq[ni][3]) * NEG - ((colb + 3 < row) ? NEG : 0.0f)) * 0.125f;
                    *reinterpret_cast<f32x4*>(&Cs[lr * 132 + wc * 64 + ni * 16 + colq]) = o;
                }
            }
            __syncthreads();
            // contiguous copy-out: 64 rows x 128 cols
#pragma unroll
            for (int v = 0; v < 8; ++v) {
                const int lr = v * 8 + cr;
                const int orow = m0 + (lr >> 5) * 64 + half * 32 + (lr & 31);
                f32x4 val = *reinterpret_cast<const f32x4*>(&Cs[lr * 132 + cc]);
                *reinterpret_cast<f32x4*>(outb + (long long)orow * 1024 + n0 + cc) = val;
            }
        }
    }
}

extern "C" void kernel_launch(void* const* d_in, const int* in_sizes, int n_in,
                              void* d_out, int out_size, void* d_ws, size_t ws_size,
                              hipStream_t stream) {
    const float* X    = (const float*)d_in[0];
    const float* pm   = (const float*)d_in[1];
    const float* W    = (const float*)d_in[2];
    const float* bias = (const float*)d_in[3];
    char* ws = (char*)d_ws;
    unsigned short* Xb = (unsigned short*)(ws + 0);          // 8192x768 bf16
    unsigned short* WT = (unsigned short*)(ws + 12582912);   // 1152x768 bf16
    unsigned short* Qb = (unsigned short*)(ws + 14352384);   // 72x1024x64 bf16
    unsigned short* Kb = (unsigned short*)(ws + 23789568);   // 72x1024x64 bf16
    float* ct = (float*)(ws + 33226752);                     // 1024x32 f32
    float* st = (float*)(ws + 33357824);                     // 1024x32 f32
    float* out = (float*)d_out;

    hipLaunchKernelGGL(k_prep, dim3(2392), dim3(256), 0, stream, X, Xb, W, WT, ct, st);
    hipLaunchKernelGGL(k_projfill, dim3(2592), dim3(512), 0, stream, Xb, WT, bias, ct, st, Qb, Kb, pm, out);
    hipLaunchKernelGGL(k_score, dim3(20, 72), dim3(256), 0, stream, Qb, Kb, pm, out);
}

// Round 21
// 102.563 us; speedup vs baseline: 1.1947x; 1.0141x over previous
//
#include <hip/hip_runtime.h>

typedef __attribute__((ext_vector_type(8))) __bf16 bf16x8;
typedef __attribute__((ext_vector_type(4))) float f32x4;

constexpr float NEG = 1000000000000.0f;  // NEG_INF

static __device__ __forceinline__ unsigned short f2bf(float f) {
    unsigned int u = __float_as_uint(f);
    u += 0x7FFFu + ((u >> 16) & 1u);   // round-to-nearest-even
    return (unsigned short)(u >> 16);
}

static __device__ __forceinline__ void gload16(const unsigned short* g, unsigned short* l) {
    __builtin_amdgcn_global_load_lds((const __attribute__((address_space(1))) void*)g,
                                     (__attribute__((address_space(3))) void*)l, 16, 0, 0);
}

// ---------------- fused prep: convX | transW | sincos ----------------
__global__ __launch_bounds__(256) void k_prep(const float* __restrict__ X,
                                              unsigned short* __restrict__ Xb,
                                              const float* __restrict__ W,
                                              unsigned short* __restrict__ WT,
                                              float* __restrict__ ct,
                                              float* __restrict__ st) {
    __shared__ __align__(16) unsigned short T[64][72];
    const int bid = blockIdx.x;
    const int tid = threadIdx.x;
    if (bid < 2048) {
        int idx = bid * 256 + tid;
        for (; idx < 1572864; idx += 2048 * 256) {
            float4 v = reinterpret_cast<const float4*>(X)[idx];
            ushort4 o;
            o.x = f2bf(v.x); o.y = f2bf(v.y); o.z = f2bf(v.z); o.w = f2bf(v.w);
            reinterpret_cast<ushort4*>(Xb)[idx] = o;
        }
    } else if (bid < 2264) {
        const int t = bid - 2048;
        const int k0 = (t % 12) * 64;
        const int c0 = (t / 12) * 64;
        const int r = tid >> 2;
        const int q = tid & 3;
        const float* src = W + (k0 + r) * 1152 + c0 + q * 16;
#pragma unroll
        for (int j = 0; j < 16; ++j)
            T[q * 16 + j][r] = f2bf(src[j]);
        __syncthreads();
        unsigned short* dst = WT + (c0 + r) * 768 + k0 + q * 16;
        *reinterpret_cast<uint4*>(dst)     = *reinterpret_cast<const uint4*>(&T[r][q * 16]);
        *reinterpret_cast<uint4*>(dst + 8) = *reinterpret_cast<const uint4*>(&T[r][q * 16 + 8]);
    } else {
        int idx = (bid - 2264) * 256 + tid;   // 0..32767
        int pos = idx >> 5, i = idx & 31;
        double inv = exp(-9.210340371976184 * (double)(2 * i) / 64.0);  // 10000^(-2i/64)
        double ang = (double)pos * inv;
        ct[idx] = (float)cos(ang);
        st[idx] = (float)sin(ang);
    }
}

// ---------------- projection (512-thread, 8-wave) + fill ----------------
__global__ __launch_bounds__(512) void k_projfill(const unsigned short* __restrict__ Xb,
                                                  const unsigned short* __restrict__ WT,
                                                  const float* __restrict__ bias,
                                                  const float* __restrict__ ct,
                                                  const float* __restrict__ st,
                                                  unsigned short* __restrict__ Qb,
                                                  unsigned short* __restrict__ Kb,
                                                  const float* __restrict__ pmask,
                                                  float* __restrict__ out) {
    __shared__ __align__(16) unsigned short As[128 * 32];
    __shared__ __align__(16) unsigned short Bs[128 * 32];
    const int bid = blockIdx.x;
    const int tid = threadIdx.x;

    if (bid >= 576) {
        // ---- fill block: one fully-masked 128x128 tile, contiguous stores --
        const int fid = bid - 576;
        const int bh = fid / 28;
        int j = fid % 28;
        int tm = 1, tn = 0;
#pragma unroll
        for (int t = 1; t < 8; ++t) {
            if (j < t) { tm = t; tn = j; break; }
            j -= t;
        }
        const int m0 = tm << 7, n0 = tn << 7;
        float* outb = out + (long long)bh * 1048576;
        const float* pm = pmask + (bh / 9) * 1024;
        const int cr = tid >> 5;             // row sub-index 0..15
        const int cc = (tid & 31) * 4;       // col 0..124
        f32x4 p = *reinterpret_cast<const f32x4*>(pm + n0 + cc);
        f32x4 o;
        o[0] = (-(1.0f - p[0]) * NEG - NEG) * 0.125f;
        o[1] = (-(1.0f - p[1]) * NEG - NEG) * 0.125f;
        o[2] = (-(1.0f - p[2]) * NEG - NEG) * 0.125f;
        o[3] = (-(1.0f - p[3]) * NEG - NEG) * 0.125f;
#pragma unroll
        for (int v = 0; v < 8; ++v) {
            const int r = v * 16 + cr;
            *reinterpret_cast<f32x4*>(outb + (long long)(m0 + r) * 1024 + n0 + cc) = o;
        }
        return;
    }

    // ---- proj block: decode XCD-congruent mapping ----
    const int x = bid & 7;               // XCD
    const int jj = bid >> 3;             // 0..71
    const int panel = (jj / 9) * 8 + x;  // 0..63
    const int h = jj % 9;
    const int lane = tid & 63;
    const int w = tid >> 6;              // 0..7
    const int wm = w >> 2;               // M-half 0..1
    const int wn = w & 3;                // N-quarter 0..3
    const int m0 = panel * 128;
    const int c0 = h * 128;

    const int l15 = lane & 15;
    const int lchunk = lane >> 4;

    const int srow = tid >> 2;           // 0..127
    const int kl = (tid & 3) ^ ((srow >> 1) & 3);
    unsigned short* ldsA = As + tid * 8;
    unsigned short* ldsB = Bs + tid * 8;
    const unsigned short* gA = Xb + (m0 + srow) * 768 + kl * 8;
    const unsigned short* gB = WT + (c0 + srow) * 768 + kl * 8;

    f32x4 acc[4][2] = {};

    for (int kt = 0; kt < 24; ++kt) {
        const int k0 = kt * 32;
        __syncthreads();
        gload16(gA + k0, ldsA);
        gload16(gB + k0, ldsB);
        __syncthreads();

        bf16x8 a[4], bfr[2];
#pragma unroll
        for (int mi = 0; mi < 4; ++mi) {
            const int row = wm * 64 + mi * 16 + l15;
            const int pc = lchunk ^ ((row >> 1) & 3);
            a[mi] = *reinterpret_cast<const bf16x8*>(As + row * 32 + pc * 8);
        }
#pragma unroll
        for (int ni = 0; ni < 2; ++ni) {
            const int row = wn * 32 + ni * 16 + l15;
            const int pc = lchunk ^ ((row >> 1) & 3);
            bfr[ni] = *reinterpret_cast<const bf16x8*>(Bs + row * 32 + pc * 8);
        }
        // swapped operands: D-row <- W cols (c128), D-col <- X rows (s)
#pragma unroll
        for (int mi = 0; mi < 4; ++mi)
#pragma unroll
            for (int ni = 0; ni < 2; ++ni)
                acc[mi][ni] = __builtin_amdgcn_mfma_f32_16x16x32_bf16(bfr[ni], a[mi], acc[mi][ni], 0, 0, 0);
    }

    // epilogue (direct scattered ushort4 — measured best, r19)
    const int qrow = (lane >> 4) << 2;
#pragma unroll
    for (int mi = 0; mi < 4; ++mi) {
        const int grow = m0 + wm * 64 + mi * 16 + l15;   // global X row
        const int bb = grow >> 10;
        const int s = grow & 1023;
        const float* cts = ct + s * 32;
        const float* sts = st + s * 32;
        const long long obase = (long long)(((bb * 9 + h) * 1024 + s)) << 6;
#pragma unroll
        for (int ni = 0; ni < 2; ++ni) {
            const int base = wn * 32 + ni * 16 + qrow;   // c128 of reg 0
            const int isK = base >> 6;
            const int d0 = base & 63;
            const int fi = d0 >> 1;
            f32x4 v = acc[mi][ni];
            f32x4 bq = *reinterpret_cast<const f32x4*>(bias + c0 + base);
            v[0] += bq[0]; v[1] += bq[1]; v[2] += bq[2]; v[3] += bq[3];
            const float cv0 = cts[fi],     sv0 = sts[fi];
            const float cv1 = cts[fi + 1], sv1 = sts[fi + 1];
            ushort4 o;
            o.x = f2bf(v[0] * cv0 - v[1] * sv0);
            o.y = f2bf(v[1] * cv0 + v[0] * sv0);
            o.z = f2bf(v[2] * cv1 - v[3] * sv1);
            o.w = f2bf(v[3] * cv1 + v[2] * sv1);
            unsigned short* dst0 = isK ? Kb : Qb;
            *reinterpret_cast<ushort4*>(dst0 + obase + d0) = o;
        }
    }
}

// ---------------- scores: XCD-congruent bh, paired tiles, LDS C-writes --
// 1D grid 1440: x = bid&7 (XCD), g = bid>>3; bh = 8*(g%9)+x, pi = g/9.
// All 20 tile-blocks of one bh land on ONE XCD consecutively -> its 96KB
// Q/K panel L2-resident across them (r13's proven locality fix).
__constant__ int PT_TM[20]  = {0,0,0,0, 1,1,1,1, 2,2,2, 3,3,3, 4,4, 5,5, 6, 7};
__constant__ int PT_TN[20]  = {0,2,4,6, 1,3,5,7, 2,4,6, 3,5,7, 4,6, 5,7, 6, 7};
__constant__ int PT_CNT[20] = {2,2,2,2, 2,2,2,1, 2,2,2, 2,2,1, 2,2, 2,1, 2, 1};

__global__ __launch_bounds__(256) void k_score(const unsigned short* __restrict__ Qb,
                                               const unsigned short* __restrict__ Kb,
                                               const float* __restrict__ pmask,
                                               float* __restrict__ out) {
    __shared__ __align__(16) float Cs[64 * 132];   // 33792 B, 16B-aligned rows
    const int bid = blockIdx.x;
    const int x = bid & 7;
    const int g = bid >> 3;
    const int bh = 8 * (g % 9) + x;
    const int pi = g / 9;               // 0..19
    const int tm = PT_TM[pi];
    const int tn0 = PT_TN[pi];
    const int cnt = PT_CNT[pi];
    const int m0 = tm << 7;
    const int tid = threadIdx.x;
    float* outb = out + (long long)bh * 1048576;
    const float* pm = pmask + (bh / 9) * 1024;

    const int lane = tid & 63;
    const int w = tid >> 6;
    const int wr = w >> 1, wc = w & 1;
    const int l15 = lane & 15;
    const int kfr = (lane >> 4) * 8;
    const unsigned short* qb = Qb + bh * 65536;
    const unsigned short* kb = Kb + bh * 65536;

    bf16x8 a[4][2];
#pragma unroll
    for (int mi = 0; mi < 4; ++mi)
#pragma unroll
        for (int kk = 0; kk < 2; ++kk)
            a[mi][kk] = *reinterpret_cast<const bf16x8*>(qb + (m0 + wr * 64 + mi * 16 + l15) * 64 + kk * 32 + kfr);

    const int colq = (lane >> 4) << 2;
    const int cr = tid >> 5;             // copy-out row sub-index 0..7
    const int cc = (tid & 31) * 4;       // copy-out col 0..124

    for (int nt = 0; nt < cnt; ++nt) {
        const int n0 = (tn0 + nt) << 7;
        bf16x8 b[4][2];
#pragma unroll
        for (int ni = 0; ni < 4; ++ni)
#pragma unroll
            for (int kk = 0; kk < 2; ++kk)
                b[ni][kk] = *reinterpret_cast<const bf16x8*>(kb + (n0 + wc * 64 + ni * 16 + l15) * 64 + kk * 32 + kfr);

        f32x4 acc[4][4] = {};
#pragma unroll
        for (int mi = 0; mi < 4; ++mi)
#pragma unroll
            for (int ni = 0; ni < 4; ++ni) {
                acc[mi][ni] = __builtin_amdgcn_mfma_f32_16x16x32_bf16(b[ni][0], a[mi][0], acc[mi][ni], 0, 0, 0);
                acc[mi][ni] = __builtin_amdgcn_mfma_f32_16x16x32_bf16(b[ni][1], a[mi][1], acc[mi][ni], 0, 0, 0);
            }

        f32x4 pmq[4];
#pragma unroll
        for (int ni = 0; ni < 4; ++ni)
            pmq[ni] = *reinterpret_cast<const f32x4*>(pm + n0 + wc * 64 + ni * 16 + colq);

#pragma unroll
        for (int half = 0; half < 2; ++half) {
            __syncthreads();   // previous copy-out (or tile) done
#pragma unroll
            for (int mi2 = 0; mi2 < 2; ++mi2) {
                const int mi = half * 2 + mi2;
                const int row = m0 + wr * 64 + mi * 16 + l15;
                const int lr = wr * 32 + mi2 * 16 + l15;      // 0..63
#pragma unroll
                for (int ni = 0; ni < 4; ++ni) {
                    const int colb = n0 + wc * 64 + ni * 16 + colq;
                    const f32x4 d = acc[mi][ni];
                    f32x4 o;
                    o[0] = (d[0] * pmq[ni][0] - (1.0f - pmq[ni][0]) * NEG - ((colb + 0 < row) ? NEG : 0.0f)) * 0.125f;
                    o[1] = (d[1] * pmq[ni][1] - (1.0f - pmq[ni][1]) * NEG - ((colb + 1 < row) ? NEG : 0.0f)) * 0.125f;
                    o[2] = (d[2] * pmq[ni][2] - (1.0f - pmq[ni][2]) * NEG - ((colb + 2 < row) ? NEG : 0.0f)) * 0.125f;
                    o[3] = (d[3] * pmq[ni][3] - (1.0f - pmq[ni][3]) * NEG - ((colb + 3 < row) ? NEG : 0.0f)) * 0.125f;
                    *reinterpret_cast<f32x4*>(&Cs[lr * 132 + wc * 64 + ni * 16 + colq]) = o;
                }
            }
            __syncthreads();
            // contiguous copy-out: 64 rows x 128 cols
#pragma unroll
            for (int v = 0; v < 8; ++v) {
                const int lr = v * 8 + cr;
                const int orow = m0 + (lr >> 5) * 64 + half * 32 + (lr & 31);
                f32x4 val = *reinterpret_cast<const f32x4*>(&Cs[lr * 132 + cc]);
                *reinterpret_cast<f32x4*>(outb + (long long)orow * 1024 + n0 + cc) = val;
            }
        }
    }
}

extern "C" void kernel_launch(void* const* d_in, const int* in_sizes, int n_in,
                              void* d_out, int out_size, void* d_ws, size_t ws_size,
                              hipStream_t stream) {
    const float* X    = (const float*)d_in[0];
    const float* pm   = (const float*)d_in[1];
    const float* W    = (const float*)d_in[2];
    const float* bias = (const float*)d_in[3];
    char* ws = (char*)d_ws;
    unsigned short* Xb = (unsigned short*)(ws + 0);          // 8192x768 bf16
    unsigned short* WT = (unsigned short*)(ws + 12582912);   // 1152x768 bf16
    unsigned short* Qb = (unsigned short*)(ws + 14352384);   // 72x1024x64 bf16
    unsigned short* Kb = (unsigned short*)(ws + 23789568);   // 72x1024x64 bf16
    float* ct = (float*)(ws + 33226752);                     // 1024x32 f32
    float* st = (float*)(ws + 33357824);                     // 1024x32 f32
    float* out = (float*)d_out;

    hipLaunchKernelGGL(k_prep, dim3(2392), dim3(256), 0, stream, X, Xb, W, WT, ct, st);
    hipLaunchKernelGGL(k_projfill, dim3(2592), dim3(512), 0, stream, Xb, WT, bias, ct, st, Qb, Kb, pm, out);
    hipLaunchKernelGGL(k_score, dim3(1440), dim3(256), 0, stream, Qb, Kb, pm, out);
}